// Round 2
// 71.104 us; speedup vs baseline: 1.0132x; 1.0132x over previous
//
#include <hip/hip_runtime.h>

// SmoothnessLoss: smooth[i] = sum_{j<64} |x[i+j] - mean_j(x[i+j])| for both inputs,
// out = mean((smoothHat - smoothY)^2) over W = N-k-1 windows. k fixed at 64.
//
// R15 = R14 resubmitted verbatim (R14's bench died to a container-acquisition
// failure, not a kernel verdict — no compile error, no absmax, no profile).
// R14 = R13 (session champion, ~72us) + two micro-polish edits:
//  (a) k2 at 1024 threads: 977 partials read in ONE load round (was 4 serial
//      dependent grid-stride rounds at ~500cy each). R12's regression was the
//      single-WAVE final kernel (16 serial rounds); this goes the other way.
//  (b) k1 window-0 sum folded into the unrolled load loop (safe path) so the
//      compiler consumes loads with incremental vmcnt instead of draining
//      all 18 loads before the sum pass.
// Session verdicts (unchanged):
//  - Direct-global C=8 wave-split is the best k1 shape (~8us, invariant):
//    R9 (LDS C=8), R10 (LDS C=4 + wave-split) both regressed vs it.
//  - Same-address atomicAdd was a serialized ~12us tail (R1-R7);
//    per-block ws store + block-level reduce kernel is strictly better (R8).
//  - Last-block spin-fusion (R11) regressed +4us; single-wave final (R12) +2us.
//  - R5: forced __launch_bounds__ occupancy caps -> scratch spills. No caps.
// HARD-WON (R3): e[] register promotion needs fully-unrolled code with
// constant private-array indices; runtime private indices demote to scratch.
// Floor decomposition: ~58us harness re-poison (268MB d_ws fill at ~41us, 82%
// HBM peak) + ~8us k1 (3.7us VALU issue + ~1.5-2us cold-HBM first-load stall,
// structural: poison evicts L2/L3 every iteration and abs-dev needs the full
// 64-elem window before any compute) + ~3us k2/dispatch.

#define K     64
#define C     8                  // windows per thread
#define HALF  128                // threads per array half
#define BLK   (2 * HALF)
#define WPB   (HALF * C)         // 1024 windows per block
#define NLD   ((K + C) / 4)      // 18 float4 loads per thread (e[72])

__global__ __launch_bounds__(BLK) void smoothness_partial_kernel(
    const float* __restrict__ yHat, const float* __restrict__ y,
    float* __restrict__ ws, int N, int W)
{
    __shared__ __align__(16) float4 xch[2 * HALF];  // y-half's d[8] per thread (4 KB)
    __shared__ float wave_sums[BLK / 64];

    const int base = blockIdx.x * WPB;           // multiple of 1024 floats
    const int tid  = threadIdx.x;
    const int half = __builtin_amdgcn_readfirstlane(tid >> 7);  // wave-uniform
    const int lt   = tid & (HALF - 1);
    const int w0   = base + lt * C;

    const float* g  = half ? y : yHat;           // SGPR base select
    const int    f0 = (base >> 2) + 2 * lt;      // first float4 idx (32B-aligned)
    const float4* p = (const float4*)g + f0;

    // Load 72-float window straight into registers (18 coalesced dwordx4).
    // Window-0 sum (loads 0..15) accumulates inline so the compiler can wait
    // with incremental vmcnt instead of draining all loads first.
    float e[K + C];
    float a0 = 0.f, a1 = 0.f, a2 = 0.f, a3 = 0.f;
    const bool safe = (base + WPB + K) <= N;     // block-uniform
    if (safe) {
        #pragma unroll
        for (int j = 0; j < NLD; ++j) {
            float4 t = p[j];
            e[4 * j + 0] = t.x; e[4 * j + 1] = t.y;
            e[4 * j + 2] = t.z; e[4 * j + 3] = t.w;
            if (j < K / 4) {                     // compile-time predicate
                a0 += t.x; a1 += t.y; a2 += t.z; a3 += t.w;
            }
        }
    } else {
        const int fmax = N >> 2;                 // N % 4 == 0
        #pragma unroll
        for (int j = 0; j < NLD; ++j) {
            float4 t = make_float4(0.f, 0.f, 0.f, 0.f);
            if (f0 + j < fmax) t = p[j];         // zero-fill: only discarded
            e[4 * j + 0] = t.x; e[4 * j + 1] = t.y;   // windows (>=W) touch it
            e[4 * j + 2] = t.z; e[4 * j + 3] = t.w;
        }
        #pragma unroll
        for (int j = 0; j < K; j += 4) {
            a0 += e[j + 0]; a1 += e[j + 1]; a2 += e[j + 2]; a3 += e[j + 3];
        }
    }

    float sums[C];
    sums[0] = (a0 + a1) + (a2 + a3);
    #pragma unroll
    for (int c = 1; c < C; ++c)
        sums[c] = sums[c - 1] + (e[K + c - 1] - e[c - 1]);

    // abs-dev per window (fabs folds into src modifier): the VALU floor
    float d[C];
    #pragma unroll
    for (int c = 0; c < C; ++c) {
        const float m = sums[c] * (1.0f / K);
        float d0 = 0.f, d1 = 0.f, d2 = 0.f, d3 = 0.f;
        #pragma unroll
        for (int j = 0; j < K; j += 4) {
            d0 += fabsf(e[c + j + 0] - m);
            d1 += fabsf(e[c + j + 1] - m);
            d2 += fabsf(e[c + j + 2] - m);
            d3 += fabsf(e[c + j + 3] - m);
        }
        d[c] = (d0 + d1) + (d2 + d3);
    }

    // y-half hands its 8 smoothness values to the yHat-half
    float part = 0.f;
    if (half) {
        xch[2 * lt + 0] = make_float4(d[0], d[1], d[2], d[3]);
        xch[2 * lt + 1] = make_float4(d[4], d[5], d[6], d[7]);
    }
    __syncthreads();
    if (!half) {
        const float4 b0 = xch[2 * lt + 0];
        const float4 b1 = xch[2 * lt + 1];
        const float dB[C] = {b0.x, b0.y, b0.z, b0.w, b1.x, b1.y, b1.z, b1.w};
        #pragma unroll
        for (int c = 0; c < C; ++c) {
            if (w0 + c < W) {
                const float diff = d[c] - dB[c];
                part += diff * diff;
            }
        }
    }

    // wave-64 shuffle reduction -> per-wave LDS -> ONE PLAIN STORE per block
    #pragma unroll
    for (int off = 32; off > 0; off >>= 1)
        part += __shfl_down(part, off, 64);

    const int lane = tid & 63;
    const int wv   = tid >> 6;
    if (lane == 0) wave_sums[wv] = part;
    __syncthreads();

    if (tid == 0) {
        float ssum = 0.f;
        #pragma unroll
        for (int i = 0; i < BLK / 64; ++i) ssum += wave_sums[i];
        ws[blockIdx.x] = ssum;                   // distinct address: no contention
    }
}

__global__ __launch_bounds__(1024) void smoothness_final_kernel(
    const float* __restrict__ ws, float* __restrict__ out, int nb, float invW)
{
    __shared__ float wave_sums[16];
    const int tid = threadIdx.x;

    // nb = 977 <= 1024: exactly ONE load round (R13 did 4 serial rounds).
    float s = 0.f;
    for (int i = tid; i < nb; i += 1024) s += ws[i];

    #pragma unroll
    for (int off = 32; off > 0; off >>= 1)
        s += __shfl_down(s, off, 64);

    if ((tid & 63) == 0) wave_sums[tid >> 6] = s;
    __syncthreads();

    if (tid < 64) {
        float t = (tid < 16) ? wave_sums[tid] : 0.f;
        #pragma unroll
        for (int off = 8; off > 0; off >>= 1)
            t += __shfl_down(t, off, 64);
        if (tid == 0) out[0] = t * invW;         // pure store: no d_out memset needed
    }
}

extern "C" void kernel_launch(void* const* d_in, const int* in_sizes, int n_in,
                              void* d_out, int out_size, void* d_ws, size_t ws_size,
                              hipStream_t stream) {
    const float* yHat = (const float*)d_in[0];
    const float* y    = (const float*)d_in[1];
    float* out        = (float*)d_out;
    float* ws         = (float*)d_ws;

    const int N = in_sizes[0];     // 1,000,000
    const int W = N - K - 1;       // 999,935
    const float invW = 1.0f / (float)W;

    const int grid = (W + WPB - 1) / WPB;           // 977 blocks
    smoothness_partial_kernel<<<grid, BLK, 0, stream>>>(yHat, y, ws, N, W);
    smoothness_final_kernel<<<1, 1024, 0, stream>>>(ws, out, grid, invW);
}